// Round 2
// baseline (346.263 us; speedup 1.0000x reference)
//
#include <hip/hip_runtime.h>
#include <cstdint>

// Problem constants
#define U_UNITS 64
#define M_SLOTS 8192
#define D_DIM   64
#define SCH     16                // softmax split-K chunks per unit
#define CHUNK   (M_SLOTS / SCH)   // 512 slots per chunk
#define BLK     256

// ---------------------------------------------------------------------------
// Kernel A: scores = (attentions · attention), masked, /tmpr.
// Scaled scores are staged into the WEIGHTS output region (same [U][M] f32
// shape); pv_kernel later reads them and overwrites with final weights.
// grid = U*SCH blocks, 256 threads. Each block: 512 slots of one unit.
// Lane layout: 16 lanes per slot, each lane covers 4 consecutive f32 (float4).
// ---------------------------------------------------------------------------
__global__ __launch_bounds__(BLK) void score_kernel(
    const float* __restrict__ att,    // [U][D] f32
    const float* __restrict__ atts,   // [U][M][D] f32
    const float* __restrict__ tmpr,   // [U] f32
    const int*   __restrict__ mask,   // [U][M] int32 (nonzero -> dropped)
    float* __restrict__ wsc,          // [U][M] scaled scores (aliases weights out)
    float* __restrict__ pmax,         // [U*SCH]
    float* __restrict__ psum)         // [U*SCH]
{
    const int b = blockIdx.x;
    const int u = b / SCH, c = b % SCH;
    const int tid = threadIdx.x;

    __shared__ float s_att[D_DIM];
    __shared__ float s_w[CHUNK];
    __shared__ float s_m[4], s_s[4];

    if (tid < D_DIM) s_att[tid] = att[u * D_DIM + tid];
    __syncthreads();

    const int cg = (tid & 15) * 4;        // column-group start (4 floats)
    float a0 = s_att[cg], a1 = s_att[cg + 1], a2 = s_att[cg + 2], a3 = s_att[cg + 3];
    const float invt = 1.0f / tmpr[u];

    const float* base = atts + (size_t)u * M_SLOTS * D_DIM + (size_t)c * CHUNK * D_DIM;

    #pragma unroll 4
    for (int k = 0; k < CHUNK / 16; ++k) {          // 32 iterations, 16 slots each
        const int sl = k * 16 + (tid >> 4);
        const float4 v = *(const float4*)(base + (size_t)sl * D_DIM + cg);
        float d = v.x * a0 + v.y * a1 + v.z * a2 + v.w * a3;
        d += __shfl_xor(d, 1);
        d += __shfl_xor(d, 2);
        d += __shfl_xor(d, 4);
        d += __shfl_xor(d, 8);
        const int m_idx = c * CHUNK + sl;
        const float wv = mask[u * M_SLOTS + m_idx] ? -1e30f : d * invt;
        if ((tid & 15) == 0) {
            s_w[sl] = wv;
            wsc[(size_t)u * M_SLOTS + m_idx] = wv;
        }
    }
    __syncthreads();

    // block max over 512 scores
    float mx = -1e30f;
    for (int i = tid; i < CHUNK; i += BLK) mx = fmaxf(mx, s_w[i]);
    #pragma unroll
    for (int off = 1; off < 64; off <<= 1) mx = fmaxf(mx, __shfl_xor(mx, off));
    if ((tid & 63) == 0) s_m[tid >> 6] = mx;
    __syncthreads();
    mx = fmaxf(fmaxf(s_m[0], s_m[1]), fmaxf(s_m[2], s_m[3]));

    // block sum of exp
    float sm = 0.f;
    for (int i = tid; i < CHUNK; i += BLK) sm += __expf(s_w[i] - mx);
    #pragma unroll
    for (int off = 1; off < 64; off <<= 1) sm += __shfl_xor(sm, off);
    if ((tid & 63) == 0) s_s[tid >> 6] = sm;
    __syncthreads();
    if (tid == 0) {
        pmax[b] = mx;
        psum[b] = s_s[0] + s_s[1] + s_s[2] + s_s[3];
    }
}

// ---------------------------------------------------------------------------
// Kernel B: combine per-chunk stats -> global max + inverse denominator per unit
// grid = 1, block = 64 (thread u handles unit u)
// ---------------------------------------------------------------------------
__global__ void combine_kernel(const float* __restrict__ pmax,
                               const float* __restrict__ psum,
                               float* __restrict__ gmx,
                               float* __restrict__ ginv)
{
    const int u = threadIdx.x;
    float mx = -1e30f;
    #pragma unroll
    for (int c = 0; c < SCH; ++c) mx = fmaxf(mx, pmax[u * SCH + c]);
    float s = 0.f;
    #pragma unroll
    for (int c = 0; c < SCH; ++c) s += psum[u * SCH + c] * __expf(pmax[u * SCH + c] - mx);
    gmx[u] = mx;
    ginv[u] = 1.0f / s;
}

// ---------------------------------------------------------------------------
// Kernel C: weights (f32, overwrite the staged scores) + PV partial
// accumulation + memories pass-through copy. memories read ONCE.
// grid = U*SCH, 256 threads.
// ---------------------------------------------------------------------------
__global__ __launch_bounds__(BLK) void pv_kernel(
    const float* __restrict__ mem,    // [U][M][D] f32
    const float* __restrict__ gmx,
    const float* __restrict__ ginv,
    float* __restrict__ out_w,        // [U][M] f32: read staged score, write weight
    float* __restrict__ out_m,        // [U][M][D] f32
    float* __restrict__ pout)         // [U*SCH][D]
{
    const int b = blockIdx.x;
    const int u = b / SCH, c = b % SCH;
    const int tid = threadIdx.x;
    const float gm = gmx[u], gi = ginv[u];
    const int cg = (tid & 15) * 4;

    float acc[4] = {0.f, 0.f, 0.f, 0.f};
    const size_t ubase = (size_t)u * M_SLOTS * D_DIM + (size_t)c * CHUNK * D_DIM;

    #pragma unroll 4
    for (int k = 0; k < CHUNK / 16; ++k) {
        const int sl = k * 16 + (tid >> 4);
        const int m_idx = c * CHUNK + sl;
        const float sc = out_w[(size_t)u * M_SLOTS + m_idx];   // staged score (read before write)
        const float wv = __expf(sc - gm) * gi;
        const float4 v = *(const float4*)(mem + ubase + (size_t)sl * D_DIM + cg);
        *(float4*)(out_m + ubase + (size_t)sl * D_DIM + cg) = v;   // pass-through copy
        acc[0] += wv * v.x;
        acc[1] += wv * v.y;
        acc[2] += wv * v.z;
        acc[3] += wv * v.w;
        if ((tid & 15) == 0) out_w[(size_t)u * M_SLOTS + m_idx] = wv;
    }

    // reduce across the 4 slot-subgroups within each wave (xor bits 4,5)
    #pragma unroll
    for (int j = 0; j < 4; ++j) {
        acc[j] += __shfl_xor(acc[j], 16);
        acc[j] += __shfl_xor(acc[j], 32);
    }

    __shared__ float s_acc[4 * D_DIM];
    const int lane = tid & 63, w = tid >> 6;
    if (lane < 16) {
        #pragma unroll
        for (int j = 0; j < 4; ++j) s_acc[w * D_DIM + lane * 4 + j] = acc[j];
    }
    __syncthreads();
    if (tid < D_DIM) {
        const float s = s_acc[tid] + s_acc[D_DIM + tid] + s_acc[2 * D_DIM + tid] + s_acc[3 * D_DIM + tid];
        pout[(size_t)b * D_DIM + tid] = s;
    }
}

// ---------------------------------------------------------------------------
// Kernel D: reduce chunk partials -> outputs [U][D] f32
// ---------------------------------------------------------------------------
__global__ void out_kernel(const float* __restrict__ pout, float* __restrict__ out_o)
{
    const int u = blockIdx.x, t = threadIdx.x;   // 64 x 64
    float s = 0.f;
    #pragma unroll
    for (int c = 0; c < SCH; ++c) s += pout[((size_t)u * SCH + c) * D_DIM + t];
    out_o[u * D_DIM + t] = s;
}

extern "C" void kernel_launch(void* const* d_in, const int* in_sizes, int n_in,
                              void* d_out, int out_size, void* d_ws, size_t ws_size,
                              hipStream_t stream)
{
    const float* att  = (const float*)d_in[0];  // attention  [64,64]
    const float* atts = (const float*)d_in[1];  // attentions [64,8192,64]
    const float* mem  = (const float*)d_in[2];  // memories   [64,8192,64]
    const float* tmpr = (const float*)d_in[3];  // tmpr       [64,1]
    const int*   mask = (const int*)d_in[4];    // mask       [64,8192]

    float* out   = (float*)d_out;
    float* out_o = out;                                   // outputs  [64,64]
    float* out_w = out + U_UNITS * D_DIM;                 // weights  [64,8192]
    float* out_m = out_w + (size_t)U_UNITS * M_SLOTS;     // memories [64,8192,64]

    float* ws   = (float*)d_ws;
    float* pmax = ws;                                 // U*SCH
    float* psum = pmax + U_UNITS * SCH;               // U*SCH
    float* gmx  = psum + U_UNITS * SCH;               // U
    float* ginv = gmx + U_UNITS;                      // U
    float* pout = ginv + U_UNITS;                     // U*SCH*D

    // Stage scaled scores in the weights output region (exact [U][M] f32 fit);
    // pv_kernel reads each staged score then overwrites it with the weight.
    score_kernel<<<U_UNITS * SCH, BLK, 0, stream>>>(att, atts, tmpr, mask, out_w, pmax, psum);
    combine_kernel<<<1, U_UNITS, 0, stream>>>(pmax, psum, gmx, ginv);
    pv_kernel<<<U_UNITS * SCH, BLK, 0, stream>>>(mem, gmx, ginv, out_w, out_m, pout);
    out_kernel<<<U_UNITS, D_DIM, 0, stream>>>(pout, out_o);
}